// Round 4
// baseline (334.058 us; speedup 1.0000x reference)
//
#include <hip/hip_runtime.h>
#include <math.h>

// Problem constants
#define B_ 2
#define T_ 2048
#define C_ 1024
#define H_ 16
#define HD_ 64

typedef __bf16 bf16;
typedef __bf16 bf8v __attribute__((ext_vector_type(8)));
typedef __bf16 bf4v __attribute__((ext_vector_type(4)));
typedef float  f4v  __attribute__((ext_vector_type(4)));

#define MFMA16(a,b,c) __builtin_amdgcn_mfma_f32_16x16x32_bf16((a),(b),(c),0,0,0)

typedef const __attribute__((address_space(1))) void* gas_ptr;
typedef __attribute__((address_space(3))) void*       las_ptr;

static __device__ __forceinline__ void gload_lds16(const void* g, void* l) {
  __builtin_amdgcn_global_load_lds((gas_ptr)g, (las_ptr)l, 16, 0, 0);
}

// ---------------- f32 -> bf16 elementwise convert (4 elems/thread) ----------------
__global__ void k_convert(const float* __restrict__ in, bf16* __restrict__ outb, int n4) {
  int stride = gridDim.x * blockDim.x;
  for (int i = blockIdx.x * blockDim.x + threadIdx.x; i < n4; i += stride) {
    float4 v = reinterpret_cast<const float4*>(in)[i];
    bf4v o; o[0] = (bf16)v.x; o[1] = (bf16)v.y; o[2] = (bf16)v.z; o[3] = (bf16)v.w;
    reinterpret_cast<bf4v*>(outb)[i] = o;
  }
}

// ---------------- transpose f32 [R][Cc] -> bf16 [Cc][R] ----------------
__global__ void k_transpose_bf(const float* __restrict__ in, bf16* __restrict__ outb, int R, int Cc) {
  __shared__ float t[32][33];
  int c0 = blockIdx.x * 32, r0 = blockIdx.y * 32;
  int tx = threadIdx.x, ty = threadIdx.y;
  for (int i = ty; i < 32; i += 8)
    t[i][tx] = in[(size_t)(r0 + i) * Cc + c0 + tx];
  __syncthreads();
  for (int i = ty; i < 32; i += 8)
    outb[(size_t)(c0 + i) * R + r0 + tx] = (bf16)t[tx][i];
}

// ---------------- per-batch fractional positions (histogram + cumsum) ----------------
__global__ void k_positions(const int* __restrict__ tok, float* __restrict__ partial) {
  __shared__ float cnt[2048];
  __shared__ float tsum[256];
  int b = blockIdx.x, tid = threadIdx.x;
  const int* ti = tok + b * 2048;
  for (int i = tid; i < 2048; i += 256) cnt[i] = 0.f;
  __syncthreads();
  for (int i = tid; i < 2048; i += 256) atomicAdd(&cnt[ti[i]], 1.f);
  __syncthreads();
  float loc[8]; float s = 0.f;
#pragma unroll
  for (int j = 0; j < 8; ++j) { loc[j] = 1.f / cnt[ti[tid * 8 + j]]; s += loc[j]; }
  tsum[tid] = s;
  __syncthreads();
  for (int off = 1; off < 256; off <<= 1) {
    float v = (tid >= off) ? tsum[tid - off] : 0.f;
    __syncthreads();
    tsum[tid] += v;
    __syncthreads();
  }
  float run = (tid > 0) ? tsum[tid - 1] : 0.f;
  float* po = partial + b * 2048;
#pragma unroll
  for (int j = 0; j < 8; ++j) { run += loc[j]; po[tid * 8 + j] = run; }
}

// ---------------- cos/sin tables + gathered padding mask ----------------
__global__ void k_tables(const float* __restrict__ partial, const float* __restrict__ pad,
                         const int* __restrict__ tok,
                         float* __restrict__ ctab, float* __restrict__ stab, float* __restrict__ pmg) {
  int i = blockIdx.x * blockDim.x + threadIdx.x;
  if (i >= B_ * T_) return;
  int b = i >> 11;
  float p = partial[i];
  for (int d = 0; d < 32; ++d) {
    float inv = exp2f((float)d * -0.41524101186092028f);  // log2(10000)/32
    float ang = p * inv;
    float sn, cs; sincosf(ang, &sn, &cs);
    ctab[i * 32 + d] = cs; stab[i * 32 + d] = sn;
  }
  pmg[i] = pad[b * 2048 + tok[i]];
}

// ---------------- fused QKV GEMM + RoPE/fork/v-scale epilogue ----------------
// C[4096,3072] = xb @ WabT^T + bias; per-element RoPE (partner d^32 lives in same
// lane at fragment fn^2), fork overwrite, v*exp(cum); writes Qh/Kh/Vh [B,H,T,64] bf16.
__global__ __launch_bounds__(256) void k_gemm_qkv(const bf16* __restrict__ A, const bf16* __restrict__ BT,
                                                  const float* __restrict__ bias,
                                                  const float* __restrict__ ctab, const float* __restrict__ stab,
                                                  const float* __restrict__ cum,
                                                  bf16* __restrict__ Qh, bf16* __restrict__ Kh,
                                                  bf16* __restrict__ Vh) {
  const int K = 1024;
  __shared__ bf16 As[128 * 32];
  __shared__ bf16 Bs[128 * 32];
  int tid = threadIdx.x;
  int w = tid >> 6, l = tid & 63;
  int wr = w >> 1, wc = w & 1;
  int lg = l >> 4, lr = l & 15;
  int bm0 = blockIdx.y * 128, bn0 = blockIdx.x * 128;
  f4v acc[4][4] = {};
  int srow = l >> 2;
  int scol = (l & 3) * 8;
  for (int k0 = 0; k0 < K; k0 += 32) {
    __syncthreads();
#pragma unroll
    for (int i = 0; i < 2; ++i) {
      int rblk = w * 32 + i * 16;
      gload_lds16(A  + (size_t)(bm0 + rblk + srow) * K + k0 + scol, As + rblk * 32);
      gload_lds16(BT + (size_t)(bn0 + rblk + srow) * K + k0 + scol, Bs + rblk * 32);
    }
    __syncthreads();
    bf8v af[4], bb[4];
#pragma unroll
    for (int fm = 0; fm < 4; ++fm)
      af[fm] = *reinterpret_cast<const bf8v*>(As + (wr * 64 + fm * 16 + lr) * 32 + lg * 8);
#pragma unroll
    for (int fn = 0; fn < 4; ++fn)
      bb[fn] = *reinterpret_cast<const bf8v*>(Bs + (wc * 64 + fn * 16 + lr) * 32 + lg * 8);
#pragma unroll
    for (int fm = 0; fm < 4; ++fm)
#pragma unroll
      for (int fn = 0; fn < 4; ++fn)
        acc[fm][fn] = MFMA16(af[fm], bb[fn], acc[fm][fn]);
  }
  // ---- epilogue ----
  int type = bn0 >> 10;                      // 0=q, 1=k, 2=v
  int h = ((bn0 & 1023) >> 6) + wc;          // head index for this wave's 64-col block
  int cbase = bn0 + wc * 64;                 // column base (for bias)
  int r0 = bm0 + wr * 64;
  float bs[4];
#pragma unroll
  for (int fn = 0; fn < 4; ++fn) bs[fn] = bias[cbase + fn * 16 + lr];
#pragma unroll
  for (int fm = 0; fm < 4; ++fm)
#pragma unroll
    for (int j = 0; j < 4; ++j) {
      int r = r0 + fm * 16 + lg * 4 + j;     // token row
      int b = r >> 11, t = r & 2047;
      size_t obase = ((size_t)(b * 16 + h) * 2048 + t) * 64;
      float cumv = cum[r];
      if (type == 2) {
        float ve = __expf(cumv);
#pragma unroll
        for (int fn = 0; fn < 4; ++fn) {
          float val = acc[fm][fn][j] + bs[fn];
          Vh[obase + fn * 16 + lr] = (bf16)(val * ve);
        }
      } else {
        float cs0 = ctab[r * 32 + lr],      sn0 = stab[r * 32 + lr];
        float cs1 = ctab[r * 32 + 16 + lr], sn1 = stab[r * 32 + 16 + lr];
#pragma unroll
        for (int fn = 0; fn < 4; ++fn) {
          int d = fn * 16 + lr;
          float val = acc[fm][fn][j] + bs[fn];
          float par = acc[fm][fn ^ 2][j] + bs[fn ^ 2];
          float cs = (fn & 1) ? cs1 : cs0, sn = (fn & 1) ? sn1 : sn0;
          float rot = val * cs + ((fn < 2) ? -par : par) * sn;
          if (type == 0) {
            if (d == 63) rot = 1.f;
            Qh[obase + d] = (bf16)rot;
          } else {
            if (d == 63) rot = cumv;
            Kh[obase + d] = (bf16)rot;
          }
        }
      }
    }
}

// ---------------- plain GEMM: C[M,N] = A[M,K] @ BT[N,K]^T + bias (f32 out) ----------------
__global__ __launch_bounds__(256) void k_gemm_bt(const bf16* __restrict__ A, const bf16* __restrict__ BT,
                                                 const float* __restrict__ bias, float* __restrict__ Cout,
                                                 int M, int N, int K) {
  __shared__ bf16 As[128 * 32];
  __shared__ bf16 Bs[128 * 32];
  int tid = threadIdx.x;
  int w = tid >> 6, l = tid & 63;
  int wr = w >> 1, wc = w & 1;
  int lg = l >> 4, lr = l & 15;
  int bm0 = blockIdx.y * 128, bn0 = blockIdx.x * 128;
  f4v acc[4][4] = {};
  int srow = l >> 2;
  int scol = (l & 3) * 8;
  for (int k0 = 0; k0 < K; k0 += 32) {
    __syncthreads();
#pragma unroll
    for (int i = 0; i < 2; ++i) {
      int rblk = w * 32 + i * 16;
      gload_lds16(A  + (size_t)(bm0 + rblk + srow) * K + k0 + scol, As + rblk * 32);
      gload_lds16(BT + (size_t)(bn0 + rblk + srow) * K + k0 + scol, Bs + rblk * 32);
    }
    __syncthreads();
    bf8v af[4], bb[4];
#pragma unroll
    for (int fm = 0; fm < 4; ++fm)
      af[fm] = *reinterpret_cast<const bf8v*>(As + (wr * 64 + fm * 16 + lr) * 32 + lg * 8);
#pragma unroll
    for (int fn = 0; fn < 4; ++fn)
      bb[fn] = *reinterpret_cast<const bf8v*>(Bs + (wc * 64 + fn * 16 + lr) * 32 + lg * 8);
#pragma unroll
    for (int fm = 0; fm < 4; ++fm)
#pragma unroll
      for (int fn = 0; fn < 4; ++fn)
        acc[fm][fn] = MFMA16(af[fm], bb[fn], acc[fm][fn]);
  }
  int r0 = bm0 + wr * 64, c0 = bn0 + wc * 64;
#pragma unroll
  for (int fm = 0; fm < 4; ++fm)
#pragma unroll
    for (int fn = 0; fn < 4; ++fn)
#pragma unroll
      for (int j = 0; j < 4; ++j) {
        int r = r0 + fm * 16 + lg * 4 + j, c = c0 + fn * 16 + lr;
        Cout[(size_t)r * N + c] = acc[fm][fn][j] + bias[c];
      }
}

// ---------------- flash attention: q-tile 64 x (b,h); 4 waves x 16 q-rows ----------------
__global__ __launch_bounds__(256) void k_attn(const bf16* __restrict__ Qh, const bf16* __restrict__ Kh,
                                              const bf16* __restrict__ Vh, const float* __restrict__ pmg,
                                              bf16* __restrict__ Y) {
  __shared__ bf16 Kl[64][72];     // K tile, rows = k index (pad 72 -> 144B stride, 16B-aligned rows)
  __shared__ bf16 Vt[64][72];     // V^T tile, rows = d index
  __shared__ bf16 Pl[4][16][72];  // per-wave P re-fragment buffer
  int qt = blockIdx.x, bh = blockIdx.y;
  int b = bh >> 4;
  int tid = threadIdx.x, w = tid >> 6, l = tid & 63;
  int lg = l >> 4, lr = l & 15;
  const size_t baseT = (size_t)bh * 2048 * 64;
  int qrow_f = qt * 64 + w * 16 + lr;
  bf8v qf0 = *reinterpret_cast<const bf8v*>(Qh + baseT + (size_t)qrow_f * 64 + lg * 8);
  bf8v qf1 = *reinterpret_cast<const bf8v*>(Qh + baseT + (size_t)qrow_f * 64 + 32 + lg * 8);
  float pq[4];
#pragma unroll
  for (int j = 0; j < 4; ++j) pq[j] = pmg[b * 2048 + qt * 64 + w * 16 + lg * 4 + j];
  float m_run[4] = {-INFINITY, -INFINITY, -INFINITY, -INFINITY};
  float l_run[4] = {0.f, 0.f, 0.f, 0.f};
  f4v o_acc[4] = {};
  int kr = tid >> 2, d0 = (tid & 3) * 16;
  for (int kt = 0; kt <= qt; ++kt) {
    __syncthreads();
    const bf16* kg = Kh + baseT + (size_t)(kt * 64 + kr) * 64 + d0;
    *reinterpret_cast<bf8v*>(&Kl[kr][d0])     = *reinterpret_cast<const bf8v*>(kg);
    *reinterpret_cast<bf8v*>(&Kl[kr][d0 + 8]) = *reinterpret_cast<const bf8v*>(kg + 8);
    const bf16* vg = Vh + baseT + (size_t)(kt * 64 + kr) * 64 + d0;
    bf8v v0 = *reinterpret_cast<const bf8v*>(vg);
    bf8v v1 = *reinterpret_cast<const bf8v*>(vg + 8);
#pragma unroll
    for (int j = 0; j < 8; ++j) Vt[d0 + j][kr] = v0[j];
#pragma unroll
    for (int j = 0; j < 8; ++j) Vt[d0 + 8 + j][kr] = v1[j];
    __syncthreads();
    // S = Q K^T
    f4v sa[4] = {};
#pragma unroll
    for (int nf = 0; nf < 4; ++nf) {
      bf8v kf0 = *reinterpret_cast<const bf8v*>(&Kl[nf * 16 + lr][lg * 8]);
      bf8v kf1 = *reinterpret_cast<const bf8v*>(&Kl[nf * 16 + lr][32 + lg * 8]);
      sa[nf] = MFMA16(qf0, kf0, sa[nf]);
      sa[nf] = MFMA16(qf1, kf1, sa[nf]);
    }
    // mask + scale
    float pv[4][4];
    float mx[4] = {-INFINITY, -INFINITY, -INFINITY, -INFINITY};
#pragma unroll
    for (int nf = 0; nf < 4; ++nf) {
      int kcol = kt * 64 + nf * 16 + lr;
      float pk = pmg[b * 2048 + kcol];
#pragma unroll
      for (int j = 0; j < 4; ++j) {
        int qrow = qt * 64 + w * 16 + lg * 4 + j;
        bool ok = (kcol <= qrow) && (pq[j] != 0.f) && (pk != 0.f);
        float s = ok ? sa[nf][j] * 0.125f : -INFINITY;
        pv[nf][j] = s;
        mx[j] = fmaxf(mx[j], s);
      }
    }
    for (int off = 1; off < 16; off <<= 1)
#pragma unroll
      for (int j = 0; j < 4; ++j) mx[j] = fmaxf(mx[j], __shfl_xor(mx[j], off));
    float rs[4] = {0.f, 0.f, 0.f, 0.f};
    float scl[4];
#pragma unroll
    for (int j = 0; j < 4; ++j) {
      float mnew = fmaxf(m_run[j], mx[j]);
      scl[j] = __expf(m_run[j] - mnew);
      m_run[j] = mnew;
    }
#pragma unroll
    for (int nf = 0; nf < 4; ++nf)
#pragma unroll
      for (int j = 0; j < 4; ++j) {
        float p = __expf(pv[nf][j] - m_run[j]);
        pv[nf][j] = p;
        rs[j] += p;
      }
    for (int off = 1; off < 16; off <<= 1)
#pragma unroll
      for (int j = 0; j < 4; ++j) rs[j] += __shfl_xor(rs[j], off);
#pragma unroll
    for (int j = 0; j < 4; ++j) l_run[j] = l_run[j] * scl[j] + rs[j];
#pragma unroll
    for (int df = 0; df < 4; ++df)
#pragma unroll
      for (int j = 0; j < 4; ++j) o_acc[df][j] *= scl[j];
#pragma unroll
    for (int nf = 0; nf < 4; ++nf)
#pragma unroll
      for (int j = 0; j < 4; ++j)
        Pl[w][lg * 4 + j][nf * 16 + lr] = (bf16)pv[nf][j];
    __syncthreads();
    bf8v pa0 = *reinterpret_cast<const bf8v*>(&Pl[w][lr][lg * 8]);
    bf8v pa1 = *reinterpret_cast<const bf8v*>(&Pl[w][lr][32 + lg * 8]);
#pragma unroll
    for (int df = 0; df < 4; ++df) {
      bf8v vf0 = *reinterpret_cast<const bf8v*>(&Vt[df * 16 + lr][lg * 8]);
      bf8v vf1 = *reinterpret_cast<const bf8v*>(&Vt[df * 16 + lr][32 + lg * 8]);
      o_acc[df] = MFMA16(pa0, vf0, o_acc[df]);
      o_acc[df] = MFMA16(pa1, vf1, o_acc[df]);
    }
  }
  int h = bh & 15;
#pragma unroll
  for (int j = 0; j < 4; ++j) {
    float inv = 1.f / l_run[j];
    int trow = qt * 64 + w * 16 + lg * 4 + j;
#pragma unroll
    for (int df = 0; df < 4; ++df)
      Y[((size_t)(b * 2048 + trow) * 16 + h) * 64 + df * 16 + lr] = (bf16)(o_acc[df][j] * inv);
  }
}

// ---------------- launcher ----------------
// ws layout (bytes) — total 44,040,192 B (42 MiB), safely under a 64 MiB ws:
//   partial @ 0          : 16384
//   ctab    @ 16384      : 524288
//   stab    @ 540672     : 524288
//   pmg     @ 1064960    : 16384
//   WabT    @ 2097152    : 6291456   (3072x1024 bf16)
//   WpbT    @ 8388608    : 2097152   (1024x1024 bf16)
//   xb      @ 10485760   : 8388608   (4096x1024 bf16) -- reused as Ybf after qkv GEMM
//   Qh      @ 18874368   : 8388608   ([B,H,T,64] bf16)
//   Kh      @ 27262976   : 8388608
//   Vh      @ 35651584   : 8388608
extern "C" void kernel_launch(void* const* d_in, const int* in_sizes, int n_in,
                              void* d_out, int out_size, void* d_ws, size_t ws_size,
                              hipStream_t stream) {
  const float* x     = (const float*)d_in[0];
  const float* cum   = (const float*)d_in[1];
  const float* pad   = (const float*)d_in[2];
  const float* Wattn = (const float*)d_in[3];
  const float* battn = (const float*)d_in[4];
  const float* Wproj = (const float*)d_in[5];
  const float* bproj = (const float*)d_in[6];
  const int*   tok   = (const int*)d_in[7];
  float* out = (float*)d_out;
  char* ws = (char*)d_ws;

  float* partial = (float*)(ws);
  float* ctab    = (float*)(ws + 16384);
  float* stab    = (float*)(ws + 540672);
  float* pmg     = (float*)(ws + 1064960);
  bf16*  WabT    = (bf16*)(ws + 2097152);
  bf16*  WpbT    = (bf16*)(ws + 8388608);
  bf16*  xb      = (bf16*)(ws + 10485760);
  bf16*  Qh      = (bf16*)(ws + 18874368);
  bf16*  Kh      = (bf16*)(ws + 27262976);
  bf16*  Vh      = (bf16*)(ws + 35651584);
  bf16*  Ybf     = xb;  // xb dead after qkv GEMM

  k_convert<<<2048, 256, 0, stream>>>(x, xb, (B_ * T_ * C_) / 4);
  k_transpose_bf<<<dim3(96, 32), dim3(32, 8), 0, stream>>>(Wattn, WabT, 1024, 3072);
  k_transpose_bf<<<dim3(32, 32), dim3(32, 8), 0, stream>>>(Wproj, WpbT, 1024, 1024);
  k_positions<<<2, 256, 0, stream>>>(tok, partial);
  k_tables<<<16, 256, 0, stream>>>(partial, pad, tok, ctab, stab, pmg);
  k_gemm_qkv<<<dim3(24, 32), 256, 0, stream>>>(xb, WabT, battn, ctab, stab, cum, Qh, Kh, Vh);
  k_attn<<<dim3(32, 32), 256, 0, stream>>>(Qh, Kh, Vh, pmg, Ybf);
  k_gemm_bt<<<dim3(8, 32), 256, 0, stream>>>(Ybf, WpbT, bproj, out, 4096, 1024, 1024);
}

// Round 5
// 253.434 us; speedup vs baseline: 1.3181x; 1.3181x over previous
//
#include <hip/hip_runtime.h>
#include <math.h>

// Problem constants
#define B_ 2
#define T_ 2048
#define C_ 1024
#define H_ 16
#define HD_ 64

typedef __bf16 bf16;
typedef __bf16 bf8v __attribute__((ext_vector_type(8)));
typedef __bf16 bf4v __attribute__((ext_vector_type(4)));
typedef float  f4v  __attribute__((ext_vector_type(4)));

#define MFMA16(a,b,c) __builtin_amdgcn_mfma_f32_16x16x32_bf16((a),(b),(c),0,0,0)

typedef const __attribute__((address_space(1))) void* gas_ptr;
typedef __attribute__((address_space(3))) void*       las_ptr;

static __device__ __forceinline__ void gload_lds16(const void* g, void* l) {
  __builtin_amdgcn_global_load_lds((gas_ptr)g, (las_ptr)l, 16, 0, 0);
}

// ---------------- f32 -> bf16 elementwise convert (4 elems/thread) ----------------
__global__ void k_convert(const float* __restrict__ in, bf16* __restrict__ outb, int n4) {
  int stride = gridDim.x * blockDim.x;
  for (int i = blockIdx.x * blockDim.x + threadIdx.x; i < n4; i += stride) {
    float4 v = reinterpret_cast<const float4*>(in)[i];
    bf4v o; o[0] = (bf16)v.x; o[1] = (bf16)v.y; o[2] = (bf16)v.z; o[3] = (bf16)v.w;
    reinterpret_cast<bf4v*>(outb)[i] = o;
  }
}

// ---------------- transpose f32 [R][Cc] -> bf16 [Cc][R] ----------------
__global__ void k_transpose_bf(const float* __restrict__ in, bf16* __restrict__ outb, int R, int Cc) {
  __shared__ float t[32][33];
  int c0 = blockIdx.x * 32, r0 = blockIdx.y * 32;
  int tx = threadIdx.x, ty = threadIdx.y;
  for (int i = ty; i < 32; i += 8)
    t[i][tx] = in[(size_t)(r0 + i) * Cc + c0 + tx];
  __syncthreads();
  for (int i = ty; i < 32; i += 8)
    outb[(size_t)(c0 + i) * R + r0 + tx] = (bf16)t[tx][i];
}

// ---------------- per-batch fractional positions (histogram + cumsum) ----------------
__global__ void k_positions(const int* __restrict__ tok, float* __restrict__ partial) {
  __shared__ float cnt[2048];
  __shared__ float tsum[256];
  int b = blockIdx.x, tid = threadIdx.x;
  const int* ti = tok + b * 2048;
  for (int i = tid; i < 2048; i += 256) cnt[i] = 0.f;
  __syncthreads();
  for (int i = tid; i < 2048; i += 256) atomicAdd(&cnt[ti[i]], 1.f);
  __syncthreads();
  float loc[8]; float s = 0.f;
#pragma unroll
  for (int j = 0; j < 8; ++j) { loc[j] = 1.f / cnt[ti[tid * 8 + j]]; s += loc[j]; }
  tsum[tid] = s;
  __syncthreads();
  for (int off = 1; off < 256; off <<= 1) {
    float v = (tid >= off) ? tsum[tid - off] : 0.f;
    __syncthreads();
    tsum[tid] += v;
    __syncthreads();
  }
  float run = (tid > 0) ? tsum[tid - 1] : 0.f;
  float* po = partial + b * 2048;
#pragma unroll
  for (int j = 0; j < 8; ++j) { run += loc[j]; po[tid * 8 + j] = run; }
}

// ---------------- cos/sin tables + gathered padding mask ----------------
__global__ void k_tables(const float* __restrict__ partial, const float* __restrict__ pad,
                         const int* __restrict__ tok,
                         float* __restrict__ ctab, float* __restrict__ stab, float* __restrict__ pmg) {
  int i = blockIdx.x * blockDim.x + threadIdx.x;
  if (i >= B_ * T_) return;
  int b = i >> 11;
  float p = partial[i];
  for (int d = 0; d < 32; ++d) {
    float inv = exp2f((float)d * -0.41524101186092028f);  // log2(10000)/32
    float ang = p * inv;
    float sn, cs; sincosf(ang, &sn, &cs);
    ctab[i * 32 + d] = cs; stab[i * 32 + d] = sn;
  }
  pmg[i] = pad[b * 2048 + tok[i]];
}

// ---------------- fused QKV GEMM + RoPE/fork/v-scale epilogue ----------------
// C[4096,3072] = xb @ WabT^T + bias. Q/K: RoPE (partner d^32 is same lane, frag fn^2),
// fork overwrite -> Qh/Kh [B,H,T,64]. V: scale by exp(cum), written TRANSPOSED
// -> VhT [B*H][64][2048] via packed bf4v (j-index = 4 consecutive tokens).
__global__ __launch_bounds__(256) void k_gemm_qkv(const bf16* __restrict__ A, const bf16* __restrict__ BT,
                                                  const float* __restrict__ bias,
                                                  const float* __restrict__ ctab, const float* __restrict__ stab,
                                                  const float* __restrict__ cum,
                                                  bf16* __restrict__ Qh, bf16* __restrict__ Kh,
                                                  bf16* __restrict__ VhT) {
  const int K = 1024;
  __shared__ bf16 As[128 * 32];
  __shared__ bf16 Bs[128 * 32];
  int tid = threadIdx.x;
  int w = tid >> 6, l = tid & 63;
  int wr = w >> 1, wc = w & 1;
  int lg = l >> 4, lr = l & 15;
  int bm0 = blockIdx.y * 128, bn0 = blockIdx.x * 128;
  f4v acc[4][4] = {};
  int srow = l >> 2;
  int scol = (l & 3) * 8;
  for (int k0 = 0; k0 < K; k0 += 32) {
    __syncthreads();
#pragma unroll
    for (int i = 0; i < 2; ++i) {
      int rblk = w * 32 + i * 16;
      gload_lds16(A  + (size_t)(bm0 + rblk + srow) * K + k0 + scol, As + rblk * 32);
      gload_lds16(BT + (size_t)(bn0 + rblk + srow) * K + k0 + scol, Bs + rblk * 32);
    }
    __syncthreads();
    bf8v af[4], bb[4];
#pragma unroll
    for (int fm = 0; fm < 4; ++fm)
      af[fm] = *reinterpret_cast<const bf8v*>(As + (wr * 64 + fm * 16 + lr) * 32 + lg * 8);
#pragma unroll
    for (int fn = 0; fn < 4; ++fn)
      bb[fn] = *reinterpret_cast<const bf8v*>(Bs + (wc * 64 + fn * 16 + lr) * 32 + lg * 8);
#pragma unroll
    for (int fm = 0; fm < 4; ++fm)
#pragma unroll
      for (int fn = 0; fn < 4; ++fn)
        acc[fm][fn] = MFMA16(af[fm], bb[fn], acc[fm][fn]);
  }
  // ---- epilogue ----
  int type = bn0 >> 10;                      // 0=q, 1=k, 2=v
  int h = ((bn0 & 1023) >> 6) + wc;          // head index for this wave's 64-col block
  int cbase = bn0 + wc * 64;                 // column base (for bias)
  int r0 = bm0 + wr * 64;
  float bs[4];
#pragma unroll
  for (int fn = 0; fn < 4; ++fn) bs[fn] = bias[cbase + fn * 16 + lr];
  if (type == 2) {
#pragma unroll
    for (int fm = 0; fm < 4; ++fm) {
      int rbase = r0 + fm * 16 + lg * 4;     // 4 consecutive tokens (within one batch)
      float ve[4];
#pragma unroll
      for (int j = 0; j < 4; ++j) ve[j] = __expf(cum[rbase + j]);
      int bb2 = rbase >> 11, tt = rbase & 2047;
      size_t vbase = (size_t)(bb2 * 16 + h) * 64 * 2048 + tt;
#pragma unroll
      for (int fn = 0; fn < 4; ++fn) {
        int d = fn * 16 + lr;
        bf4v pack;
#pragma unroll
        for (int j = 0; j < 4; ++j)
          pack[j] = (bf16)((acc[fm][fn][j] + bs[fn]) * ve[j]);
        *reinterpret_cast<bf4v*>(VhT + vbase + (size_t)d * 2048) = pack;
      }
    }
  } else {
#pragma unroll
    for (int fm = 0; fm < 4; ++fm)
#pragma unroll
      for (int j = 0; j < 4; ++j) {
        int r = r0 + fm * 16 + lg * 4 + j;   // token row
        int b = r >> 11, t = r & 2047;
        size_t obase = ((size_t)(b * 16 + h) * 2048 + t) * 64;
        float cumv = cum[r];
        float cs0 = ctab[r * 32 + lr],      sn0 = stab[r * 32 + lr];
        float cs1 = ctab[r * 32 + 16 + lr], sn1 = stab[r * 32 + 16 + lr];
#pragma unroll
        for (int fn = 0; fn < 4; ++fn) {
          int d = fn * 16 + lr;
          float val = acc[fm][fn][j] + bs[fn];
          float par = acc[fm][fn ^ 2][j] + bs[fn ^ 2];
          float cs = (fn & 1) ? cs1 : cs0, sn = (fn & 1) ? sn1 : sn0;
          float rot = val * cs + ((fn < 2) ? -par : par) * sn;
          if (type == 0) {
            if (d == 63) rot = 1.f;
            Qh[obase + d] = (bf16)rot;
          } else {
            if (d == 63) rot = cumv;
            Kh[obase + d] = (bf16)rot;
          }
        }
      }
  }
}

// ---------------- plain GEMM: C[M,N] = A[M,K] @ BT[N,K]^T + bias (f32 out) ----------------
__global__ __launch_bounds__(256) void k_gemm_bt(const bf16* __restrict__ A, const bf16* __restrict__ BT,
                                                 const float* __restrict__ bias, float* __restrict__ Cout,
                                                 int M, int N, int K) {
  __shared__ bf16 As[128 * 32];
  __shared__ bf16 Bs[128 * 32];
  int tid = threadIdx.x;
  int w = tid >> 6, l = tid & 63;
  int wr = w >> 1, wc = w & 1;
  int lg = l >> 4, lr = l & 15;
  int bm0 = blockIdx.y * 128, bn0 = blockIdx.x * 128;
  f4v acc[4][4] = {};
  int srow = l >> 2;
  int scol = (l & 3) * 8;
  for (int k0 = 0; k0 < K; k0 += 32) {
    __syncthreads();
#pragma unroll
    for (int i = 0; i < 2; ++i) {
      int rblk = w * 32 + i * 16;
      gload_lds16(A  + (size_t)(bm0 + rblk + srow) * K + k0 + scol, As + rblk * 32);
      gload_lds16(BT + (size_t)(bn0 + rblk + srow) * K + k0 + scol, Bs + rblk * 32);
    }
    __syncthreads();
    bf8v af[4], bb[4];
#pragma unroll
    for (int fm = 0; fm < 4; ++fm)
      af[fm] = *reinterpret_cast<const bf8v*>(As + (wr * 64 + fm * 16 + lr) * 32 + lg * 8);
#pragma unroll
    for (int fn = 0; fn < 4; ++fn)
      bb[fn] = *reinterpret_cast<const bf8v*>(Bs + (wc * 64 + fn * 16 + lr) * 32 + lg * 8);
#pragma unroll
    for (int fm = 0; fm < 4; ++fm)
#pragma unroll
      for (int fn = 0; fn < 4; ++fn)
        acc[fm][fn] = MFMA16(af[fm], bb[fn], acc[fm][fn]);
  }
  int r0 = bm0 + wr * 64, c0 = bn0 + wc * 64;
#pragma unroll
  for (int fm = 0; fm < 4; ++fm)
#pragma unroll
    for (int fn = 0; fn < 4; ++fn)
#pragma unroll
      for (int j = 0; j < 4; ++j) {
        int r = r0 + fm * 16 + lg * 4 + j, c = c0 + fn * 16 + lr;
        Cout[(size_t)r * N + c] = acc[fm][fn][j] + bias[c];
      }
}

// ---------------- flash attention ----------------
// grid 1024 1-D, descending-work order: qt = 31 - bid/32 (heaviest blocks first).
// K and V^T tiles staged via global_load_lds w/ XOR-swizzled source (linear LDS dest,
// colblock ^= row&7 on BOTH source and read -> conflict-free ds_read_b128).
// Double-buffered, ONE barrier per tile: STAGE(kt+1) issued before compute(kt),
// loads stay in flight under QK^T+softmax+PV, drained by the end-of-tile barrier.
__global__ __launch_bounds__(256) void k_attn(const bf16* __restrict__ Qh, const bf16* __restrict__ Kh,
                                              const bf16* __restrict__ VhT, const float* __restrict__ pmg,
                                              bf16* __restrict__ Y) {
  __shared__ bf16 Kl[2][64 * 64];   // K tile: row = k-idx (128B, swizzled slots)
  __shared__ bf16 Vt[2][64 * 64];   // V^T tile: row = d (128B, swizzled slots)
  __shared__ bf16 Pl[4][16][72];    // per-wave P re-fragment (144B stride: aligned, 2-way reads)
  int bid = blockIdx.x;
  int qt = 31 - (bid >> 5);
  int bh = bid & 31;
  int b = bh >> 4;
  int tid = threadIdx.x, w = tid >> 6, l = tid & 63;
  int lg = l >> 4, lr = l & 15;
  const size_t baseK = (size_t)bh * 2048 * 64;
  const size_t baseV = (size_t)bh * 64 * 2048;
  // Q fragments (global, registers)
  int qrow_f = qt * 64 + w * 16 + lr;
  bf8v qf0 = *reinterpret_cast<const bf8v*>(Qh + baseK + (size_t)qrow_f * 64 + lg * 8);
  bf8v qf1 = *reinterpret_cast<const bf8v*>(Qh + baseK + (size_t)qrow_f * 64 + 32 + lg * 8);
  float pq[4];
#pragma unroll
  for (int j = 0; j < 4; ++j) pq[j] = pmg[b * 2048 + qt * 64 + w * 16 + lg * 4 + j];
  // staging lane geometry: 64 lanes x 16B = 8 rows of 128B; slot s holds source colblock s^row
  int lrow = l >> 3;             // row within 8-row chunk (0..7)
  int lcb  = (l & 7) ^ lrow;     // swizzled source colblock
  auto STAGE = [&](int kt, int bb) {
#pragma unroll
    for (int i = 0; i < 2; ++i) {
      int rr = w * 16 + i * 8 + lrow;   // tile-local row this lane feeds
      gload_lds16(Kh  + baseK + (size_t)(kt * 64 + rr) * 64 + lcb * 8, &Kl[bb][(w * 16 + i * 8) * 64]);
      gload_lds16(VhT + baseV + (size_t)rr * 2048 + kt * 64 + lcb * 8, &Vt[bb][(w * 16 + i * 8) * 64]);
    }
  };
  float m_run[4] = {-INFINITY, -INFINITY, -INFINITY, -INFINITY};
  float l_run[4] = {0.f, 0.f, 0.f, 0.f};
  f4v o_acc[4] = {};
  STAGE(0, 0);
  __syncthreads();
  int cur = 0;
  int sw = lr & 7;
  for (int kt = 0; kt <= qt; ++kt) {
    if (kt < qt) STAGE(kt + 1, cur ^ 1);    // prefetch next tile (in flight during compute)
    const bf16* KB = &Kl[cur][0];
    const bf16* VB = &Vt[cur][0];
    // S = Q K^T
    f4v sa[4] = {};
#pragma unroll
    for (int nf = 0; nf < 4; ++nf) {
      int R = (nf * 16 + lr) * 64;
      bf8v kf0 = *reinterpret_cast<const bf8v*>(KB + R + ((lg ^ sw) * 8));
      bf8v kf1 = *reinterpret_cast<const bf8v*>(KB + R + (((lg + 4) ^ sw) * 8));
      sa[nf] = MFMA16(qf0, kf0, sa[nf]);
      sa[nf] = MFMA16(qf1, kf1, sa[nf]);
    }
    // mask + scale
    float pv[4][4];
    float mx[4] = {-INFINITY, -INFINITY, -INFINITY, -INFINITY};
#pragma unroll
    for (int nf = 0; nf < 4; ++nf) {
      int kcol = kt * 64 + nf * 16 + lr;
      float pk = pmg[b * 2048 + kcol];
#pragma unroll
      for (int j = 0; j < 4; ++j) {
        int qrow = qt * 64 + w * 16 + lg * 4 + j;
        bool ok = (kcol <= qrow) && (pq[j] != 0.f) && (pk != 0.f);
        float s = ok ? sa[nf][j] * 0.125f : -INFINITY;
        pv[nf][j] = s;
        mx[j] = fmaxf(mx[j], s);
      }
    }
    for (int off = 1; off < 16; off <<= 1)
#pragma unroll
      for (int j = 0; j < 4; ++j) mx[j] = fmaxf(mx[j], __shfl_xor(mx[j], off));
    float rs[4] = {0.f, 0.f, 0.f, 0.f};
    float scl[4];
#pragma unroll
    for (int j = 0; j < 4; ++j) {
      float mnew = fmaxf(m_run[j], mx[j]);
      scl[j] = __expf(m_run[j] - mnew);
      m_run[j] = mnew;
    }
#pragma unroll
    for (int nf = 0; nf < 4; ++nf)
#pragma unroll
      for (int j = 0; j < 4; ++j) {
        float p = __expf(pv[nf][j] - m_run[j]);
        pv[nf][j] = p;
        rs[j] += p;
      }
    for (int off = 1; off < 16; off <<= 1)
#pragma unroll
      for (int j = 0; j < 4; ++j) rs[j] += __shfl_xor(rs[j], off);
#pragma unroll
    for (int j = 0; j < 4; ++j) l_run[j] = l_run[j] * scl[j] + rs[j];
#pragma unroll
    for (int df = 0; df < 4; ++df)
#pragma unroll
      for (int j = 0; j < 4; ++j) o_acc[df][j] *= scl[j];
    // P -> LDS (per-wave buffer; same-wave dep handled by lgkmcnt, no barrier)
#pragma unroll
    for (int nf = 0; nf < 4; ++nf)
#pragma unroll
      for (int j = 0; j < 4; ++j)
        Pl[w][lg * 4 + j][nf * 16 + lr] = (bf16)pv[nf][j];
    bf8v pa0 = *reinterpret_cast<const bf8v*>(&Pl[w][lr][lg * 8]);
    bf8v pa1 = *reinterpret_cast<const bf8v*>(&Pl[w][lr][32 + lg * 8]);
#pragma unroll
    for (int df = 0; df < 4; ++df) {
      int D = (df * 16 + lr) * 64;
      bf8v vf0 = *reinterpret_cast<const bf8v*>(VB + D + ((lg ^ sw) * 8));
      bf8v vf1 = *reinterpret_cast<const bf8v*>(VB + D + (((lg + 4) ^ sw) * 8));
      o_acc[df] = MFMA16(pa0, vf0, o_acc[df]);
      o_acc[df] = MFMA16(pa1, vf1, o_acc[df]);
    }
    __syncthreads();   // drains prefetch vmcnt + guards buffer swap
    cur ^= 1;
  }
  int h = bh & 15;
#pragma unroll
  for (int j = 0; j < 4; ++j) {
    float inv = 1.f / l_run[j];
    int trow = qt * 64 + w * 16 + lg * 4 + j;
#pragma unroll
    for (int df = 0; df < 4; ++df)
      Y[((size_t)(b * 2048 + trow) * 16 + h) * 64 + df * 16 + lr] = (bf16)(o_acc[df][j] * inv);
  }
}

// ---------------- launcher ----------------
// ws layout (bytes) — total 44,040,192 B (42 MiB):
//   partial @ 0          : 16384
//   ctab    @ 16384      : 524288
//   stab    @ 540672     : 524288
//   pmg     @ 1064960    : 16384
//   WabT    @ 2097152    : 6291456   (3072x1024 bf16)
//   WpbT    @ 8388608    : 2097152   (1024x1024 bf16)
//   xb      @ 10485760   : 8388608   (4096x1024 bf16) -- reused as Ybf after qkv GEMM
//   Qh      @ 18874368   : 8388608   ([B,H,T,64] bf16)
//   Kh      @ 27262976   : 8388608   ([B,H,T,64] bf16)
//   VhT     @ 35651584   : 8388608   ([B*H,64,T] bf16 — V transposed)
extern "C" void kernel_launch(void* const* d_in, const int* in_sizes, int n_in,
                              void* d_out, int out_size, void* d_ws, size_t ws_size,
                              hipStream_t stream) {
  const float* x     = (const float*)d_in[0];
  const float* cum   = (const float*)d_in[1];
  const float* pad   = (const float*)d_in[2];
  const float* Wattn = (const float*)d_in[3];
  const float* battn = (const float*)d_in[4];
  const float* Wproj = (const float*)d_in[5];
  const float* bproj = (const float*)d_in[6];
  const int*   tok   = (const int*)d_in[7];
  float* out = (float*)d_out;
  char* ws = (char*)d_ws;

  float* partial = (float*)(ws);
  float* ctab    = (float*)(ws + 16384);
  float* stab    = (float*)(ws + 540672);
  float* pmg     = (float*)(ws + 1064960);
  bf16*  WabT    = (bf16*)(ws + 2097152);
  bf16*  WpbT    = (bf16*)(ws + 8388608);
  bf16*  xb      = (bf16*)(ws + 10485760);
  bf16*  Qh      = (bf16*)(ws + 18874368);
  bf16*  Kh      = (bf16*)(ws + 27262976);
  bf16*  VhT    = (bf16*)(ws + 35651584);
  bf16*  Ybf     = xb;  // xb dead after qkv GEMM

  k_convert<<<2048, 256, 0, stream>>>(x, xb, (B_ * T_ * C_) / 4);
  k_transpose_bf<<<dim3(96, 32), dim3(32, 8), 0, stream>>>(Wattn, WabT, 1024, 3072);
  k_transpose_bf<<<dim3(32, 32), dim3(32, 8), 0, stream>>>(Wproj, WpbT, 1024, 1024);
  k_positions<<<2, 256, 0, stream>>>(tok, partial);
  k_tables<<<16, 256, 0, stream>>>(partial, pad, tok, ctab, stab, pmg);
  k_gemm_qkv<<<dim3(24, 32), 256, 0, stream>>>(xb, WabT, battn, ctab, stab, cum, Qh, Kh, VhT);
  k_attn<<<1024, 256, 0, stream>>>(Qh, Kh, VhT, pmg, Ybf);
  k_gemm_bt<<<dim3(8, 32), 256, 0, stream>>>(Ybf, WpbT, bproj, out, 4096, 1024, 1024);
}